// Round 5
// baseline (1581.621 us; speedup 1.0000x reference)
//
#include <hip/hip_runtime.h>
#include <math.h>

#define HID    128
#define IN_CH  271
#define SEQ    281
#define NCLS   1854
#define BATCH  256
#define M_TOT  (SEQ * BATCH)          // 71936
#define KPAD0  288                    // 271 padded to 9*32
#define NPROD  192                    // producer blocks; gru = blocks 192..255
#define XT_UNITS   1280               // (tb 0..4) x (b 0..255)
#define GEMM_UNITS 843                // 281 tt x 3 pair-units (each = 2 of 6 sub-units)

typedef __attribute__((ext_vector_type(8))) short short8;
typedef __attribute__((ext_vector_type(4))) float floatx4;

#define MFMA16(acc, a, b) acc = __builtin_amdgcn_mfma_f32_16x16x32_bf16((a), (b), (acc), 0, 0, 0)

__device__ __forceinline__ unsigned short f2bf(float f) {
    union { float f; unsigned u; } v; v.f = f;
    unsigned u = v.u;
    u += 0x7FFF + ((u >> 16) & 1);        // RNE
    return (unsigned short)(u >> 16);
}
__device__ __forceinline__ unsigned short cvt_bf16(float f) {
    unsigned r;
    asm("v_cvt_pk_bf16_f32 %0, %1, %1" : "=v"(r) : "v"(f));
    return (unsigned short)r;
}
__device__ __forceinline__ float fast_rcp(float x) {
    float r;
    asm("v_rcp_f32 %0, %1" : "=v"(r) : "v"(x));
    return r;
}
__device__ __forceinline__ float fast_sigmoid(float s) {
    return fast_rcp(1.f + __expf(-s));
}
__device__ __forceinline__ float fast_tanh(float s) {
    float e = __expf(-2.f * s);
    return __builtin_fmaf(2.f, fast_rcp(1.f + e), -1.f);
}
// LDS-only barrier: waits ds-ops but does NOT drain vmcnt.
__device__ __forceinline__ void sync_lds() {
    asm volatile("s_waitcnt lgkmcnt(0)\n\ts_barrier" ::: "memory");
}

// producer->consumer progress (cnt lives in d_out; cls overwrites it at the end)
//   cnt[0..4]  : xt units done per tb (target 256)
//   cnt[5+tt]  : gemm sub-units done for step tt (target 6)
__device__ __forceinline__ void wait_ge(int* p, int tgt) {
    while (__hip_atomic_load(p, __ATOMIC_ACQUIRE, __HIP_MEMORY_SCOPE_AGENT) < tgt)
        __builtin_amdgcn_s_sleep(8);
}
__device__ __forceinline__ void release_add(int* p, int v) {
    __hip_atomic_fetch_add(p, v, __ATOMIC_RELEASE, __HIP_MEMORY_SCOPE_AGENT);
}

// ---------------------------------------------------------------------------
// 4-row swizzled LDS h-tile (R2-verified: SQ_LDS_BANK_CONFLICT = 0):
//   element (row, k) at  row*128 + (((k>>3) ^ (2*row)) << 3) + (k&7)
// ---------------------------------------------------------------------------
__device__ __forceinline__ short8 ldsA_r4(const unsigned short* base, int l15, int kk, int quad) {
    const int row4  = l15 >> 2;
    const int chunk = (4 * kk + quad) ^ (row4 << 1);
    return *(const short8*)(base + row4 * 128 + (chunk << 3));
}
__device__ __forceinline__ int sw_idx4(int row, int c) {
    return row * 128 + ((((c >> 3) ^ (row << 1)) << 3) | (c & 7));
}

// ---------------------------------------------------------------------------
// Weight transpose+convert (unchanged) + zeroing of the progress counters.
// Runs before the fused kernel; kernel boundary flushes caches.
// ---------------------------------------------------------------------------
__global__ __launch_bounds__(256) void wt_kernel(
    const float* __restrict__ Wr0, const float* __restrict__ Wu0, const float* __restrict__ Wo0,
    const float* __restrict__ Wr1, const float* __restrict__ Wu1, const float* __restrict__ Wo1,
    unsigned short* __restrict__ Wt0, unsigned short* __restrict__ Wh0,
    unsigned short* __restrict__ Wx1, unsigned short* __restrict__ Wh1,
    int* __restrict__ cnt)
{
    const int blk  = blockIdx.x;
    const int kind = blk / 3, g = blk % 3;
    const int tid  = threadIdx.x;
    const int n0   = blockIdx.y * 4;

    if (blk == 0 && blockIdx.y == 0)
        for (int j = tid; j < 5 + SEQ; j += 256) cnt[j] = 0;

    const float* __restrict__ W =
        (kind <= 1) ? ((g == 0) ? Wr0 : (g == 1) ? Wu0 : Wo0)
                    : ((g == 0) ? Wr1 : (g == 1) ? Wu1 : Wo1);

    if (kind == 0) {
        unsigned short* __restrict__ out = Wt0 + (size_t)g * HID * KPAD0;
        for (int n = n0; n < n0 + 4; ++n)
            for (int k = tid; k < KPAD0; k += 256) {
                float v = (k < IN_CH) ? W[(size_t)k * HID + n] : 0.f;
                out[(size_t)n * KPAD0 + k] = f2bf(v);
            }
    } else {
        const int rbase = (kind == 1) ? IN_CH : (kind == 2) ? 0 : HID;
        unsigned short* __restrict__ out =
            ((kind == 1) ? Wh0 : (kind == 2) ? Wx1 : Wh1) + (size_t)g * HID * HID;
        for (int n = n0; n < n0 + 4; ++n)
            for (int k = tid; k < HID; k += 256)
                out[(size_t)n * HID + k] = f2bf(W[(size_t)(rbase + k) * HID + n]);
    }
}

// ---------------------------------------------------------------------------
// FUSED pipeline kernel: 256 blocks x 512 threads.
//   blocks 0..191  : PRODUCERS — xt (X transpose->bf16) then gemm (x-gates).
//   blocks 192..255: CONSUMERS — the R2 skewed 2-phase GRU, gated per-t.
// Co-residency: every block allocates ~full-CU registers (launch_bounds(512,2)
// caps 256 unified VGPR/wave; 8 waves ~ 2016 regs) -> exactly 1 block/CU ->
// all 256 blocks resident; flag-waiting cannot deadlock.
// Producer order: xt tb=0 -> gemm tt<64 -> xt rest -> gemm rest, so XG[0]
// exists ~10us in and gru has 64 steps of runway.
// Visibility: release-add after __syncthreads (L2 writeback, cross-XCD);
// consumers acquire. gru hides poll latency: tid0 relaxed-polls t+2 at iter
// top (waits hidden under Phase A), publishes monotone rdy_t at the Phase-A
// barrier; fast path pays only an acquire fence (vmcnt already drained);
// blocking wait_ge fallback self-heals rdy_t.
// ---------------------------------------------------------------------------
__global__ __launch_bounds__(512, 2) void fused_all(
    const float* __restrict__ X,
    unsigned short* __restrict__ Abf,
    const unsigned short* __restrict__ Wt0,
    const float* __restrict__ br0, const float* __restrict__ bu0, const float* __restrict__ bo0,
    float* __restrict__ XG,
    const unsigned short* __restrict__ Wh0,
    const unsigned short* __restrict__ Wx1,
    const unsigned short* __restrict__ Wh1,
    const float* __restrict__ br1, const float* __restrict__ bu1, const float* __restrict__ bo1,
    float* __restrict__ H1fin,
    int* __restrict__ cnt)
{
    __shared__ __attribute__((aligned(16))) char smem[40960];
    __shared__ int rdy_t;
    const int bid = blockIdx.x;
    const int tid = threadIdx.x;

    if (bid < NPROD) {
        // =================== PRODUCER ===================
        const int pid = bid;

        // ---- xt unit: transpose+convert X[b][k][t0..t0+63] -> Abf
        auto xt_unit = [&](int u) {
            const int tb = u >> 8, b = u & 255;
            const int t0 = tb * 64;
            const float* Xb = X + (size_t)b * (IN_CH * SEQ);
            float (*Xl)[65] = (float (*)[65])smem;
            for (int kc = 0; kc < KPAD0 / 32; ++kc) {
#pragma unroll
                for (int r = 0; r < 4; ++r) {
                    int e = tid + 512 * r;
                    int kk = e >> 6, tt = e & 63;
                    int k = kc * 32 + kk, t = t0 + tt;
                    Xl[kk][tt] = (k < IN_CH && t < SEQ) ? Xb[k * SEQ + t] : 0.f;
                }
                __syncthreads();
                if (tid < 256) {
                    int tt = tid >> 2, part = tid & 3, t = t0 + tt;
                    if (t < SEQ) {
                        union { unsigned short s[8]; uint4 v; } uu;
#pragma unroll
                        for (int i2 = 0; i2 < 8; ++i2) uu.s[i2] = f2bf(Xl[part * 8 + i2][tt]);
                        *(uint4*)(Abf + ((size_t)b * SEQ + t) * KPAD0 + kc * 32 + part * 8) = uu.v;
                    }
                }
                __syncthreads();
            }
            if (tid == 0) release_add(&cnt[tb], 1);
        };

        // ---- gemm pair-unit: 512 thr = two independent 256-thr sub-units.
        // pair p: tt = p/3; sub-units s = (p%3)*2 + half -> g = s>>1, bh = s&1.
        const int half = tid >> 8, t2 = tid & 255;
        unsigned short* As = (unsigned short*)(smem + half * 20480);
        unsigned short* Bs = As + 5120;
        const int lane  = t2 & 63;
        const int wave  = t2 >> 6;
        const int l15   = lane & 15;
        const int quad  = lane >> 4;
        const int mhalf = wave >> 1;
        const int nhalf = wave & 1;
        const int r0 = t2 >> 2, p0 = t2 & 3;
        const int r1 = r0 + 64;

        auto gemm_unit = [&](int p) {
            const int tt  = p / 3;
            const int s   = (p % 3) * 2 + half;
            const int g   = s >> 1;
            const int b0m = (s & 1) * 128;
            const unsigned short* Bw = Wt0 + (size_t)g * HID * KPAD0;
            const float* bias = (g == 0) ? br0 : (g == 1) ? bu0 : bo0;

            wait_ge(&cnt[tt >> 6], 256);            // A rows (.,tt) need xt tb done

            floatx4 acc[4][4];
#pragma unroll
            for (int im = 0; im < 4; ++im)
#pragma unroll
                for (int in = 0; in < 4; ++in) acc[im][in] = (floatx4)0.f;

            for (int kt = 0; kt < KPAD0 / 32; ++kt) {
                __syncthreads();                     // guards As/Bs reuse (incl. cross-unit)
                const int kb = kt * 32;
                uint4 va0 = *(const uint4*)(Abf + ((size_t)(b0m + r0) * SEQ + tt) * KPAD0 + kb + p0 * 8);
                uint4 va1 = *(const uint4*)(Abf + ((size_t)(b0m + r1) * SEQ + tt) * KPAD0 + kb + p0 * 8);
                uint4 vb0 = *(const uint4*)(Bw + (size_t)r0 * KPAD0 + kb + p0 * 8);
                uint4 vb1 = *(const uint4*)(Bw + (size_t)r1 * KPAD0 + kb + p0 * 8);
                *(uint4*)(As + r0 * 40 + p0 * 8) = va0;
                *(uint4*)(As + r1 * 40 + p0 * 8) = va1;
                *(uint4*)(Bs + r0 * 40 + p0 * 8) = vb0;
                *(uint4*)(Bs + r1 * 40 + p0 * 8) = vb1;
                __syncthreads();

                short8 bf[4];
#pragma unroll
                for (int in = 0; in < 4; ++in)
                    bf[in] = *(const short8*)(Bs + (nhalf * 64 + in * 16 + l15) * 40 + quad * 8);
#pragma unroll
                for (int im = 0; im < 4; ++im) {
                    short8 af = *(const short8*)(As + (mhalf * 64 + im * 16 + l15) * 40 + quad * 8);
#pragma unroll
                    for (int in = 0; in < 4; ++in)
                        MFMA16(acc[im][in], af, bf[in]);
                }
            }

            float bv[4];
#pragma unroll
            for (int in = 0; in < 4; ++in) bv[in] = bias[nhalf * 64 + in * 16 + l15];
#pragma unroll
            for (int im = 0; im < 4; ++im) {
                const int bb = b0m + mhalf * 64 + im * 16 + quad * 4;
#pragma unroll
                for (int in = 0; in < 4; ++in) {
                    const int n = nhalf * 64 + in * 16 + l15;
                    float4 v = make_float4(acc[im][in][0] + bv[in], acc[im][in][1] + bv[in],
                                           acc[im][in][2] + bv[in], acc[im][in][3] + bv[in]);
                    float* dst = XG + ((size_t)(bb >> 2) * SEQ + tt) * 1536 + ((size_t)g * HID + n) * 4;
                    *(float4*)dst = v;
                }
            }
            __syncthreads();
            if (tid == 0) release_add(&cnt[5 + tt], 2);
        };

        // ---- 4-phase order: tb=0 first, then gemm tt<64, then the rest
        for (int u = pid; u < 256; u += NPROD)        xt_unit(u);
        for (int p = pid; p < NPROD; p += NPROD)      gemm_unit(p);   // p = pid: tt 0..63
        for (int u = 256 + pid; u < XT_UNITS; u += NPROD)   xt_unit(u);
        for (int p = NPROD + pid; p < GEMM_UNITS; p += NPROD) gemm_unit(p);

    } else {
        // =================== GRU CONSUMER (R2 body + gated prefetch) ===================
        const int gb   = bid - NPROD;     // 0..63
        const int b0   = gb * 4;
        const int w    = tid >> 6;
        const int lane = tid & 63;
        const int l15  = lane & 15;
        const int quad = lane >> 4;       // this lane's batch row 0..3
        const int c    = w * 16 + l15;    // this lane's column 0..127

        unsigned short* Hbf0 = (unsigned short*)smem;
        unsigned short* Rbf0 = Hbf0 + 512;
        unsigned short* Hbf1 = Hbf0 + 1024;
        unsigned short* Rbf1 = Hbf0 + 1536;
        int* cnt5 = cnt + 5;

        // hoisted weight B-fragments: 9 (layer,gate) tiles x 4 k-steps (AGPRs)
        short8 B0r[4], B0u[4], B0o[4], Bxr[4], Bxu[4], Bxo[4], B1r[4], B1u[4], B1o[4];
#pragma unroll
        for (int kk = 0; kk < 4; ++kk) {
            const size_t off = (size_t)c * HID + kk * 32 + quad * 8;
            B0r[kk] = *(const short8*)(Wh0 + off);
            B0u[kk] = *(const short8*)(Wh0 + (size_t)128 * HID + off);
            B0o[kk] = *(const short8*)(Wh0 + (size_t)256 * HID + off);
            Bxr[kk] = *(const short8*)(Wx1 + off);
            Bxu[kk] = *(const short8*)(Wx1 + (size_t)128 * HID + off);
            Bxo[kk] = *(const short8*)(Wx1 + (size_t)256 * HID + off);
            B1r[kk] = *(const short8*)(Wh1 + off);
            B1u[kk] = *(const short8*)(Wh1 + (size_t)128 * HID + off);
            B1o[kk] = *(const short8*)(Wh1 + (size_t)256 * HID + off);
        }
        Hbf0[tid] = 0; Rbf0[tid] = 0; Hbf1[tid] = 0; Rbf1[tid] = 0;

        float h0s = 0.f, h1s = 0.f, ug0s = 0.f, ug1s = 0.f;
        const float br1c = br1[c], bu1c = bu1[c], bo1c = bo1[c];
        const int swi = sw_idx4(quad, c);

        // prime: t=0 and t=1 ready before entering the pipelined-poll loop
        wait_ge(&cnt5[0], 6);
        wait_ge(&cnt5[1], 6);
        if (tid == 0) rdy_t = 1;

        const float* xgp = XG + (size_t)gb * SEQ * 1536 + (size_t)c * 4 + quad;
        float xr = xgp[0];
        float xu = xgp[512];
        float xo = xgp[1024];
        xgp += 1536;
        __syncthreads();

        for (int i = 0; i <= SEQ; ++i) {
            const bool l0 = (i < SEQ);
            const bool l1 = (i > 0);
            const bool pf = (i + 1 < SEQ);
            const int  tp = i + 2;

            // issue relaxed poll for t+2 (latency hides under Phase A)
            int pollv = -1;
            if (tid == 0 && tp < SEQ)
                pollv = __hip_atomic_load(&cnt5[tp], __ATOMIC_RELAXED, __HIP_MEMORY_SCOPE_AGENT);

            // ---- Phase A: read h0(i-1)/h1(i-2) once; all r,u gates + L1 o-x part
            short8 a0[4], a1[4];
#pragma unroll
            for (int kk = 0; kk < 4; ++kk) {
                a0[kk] = ldsA_r4(Hbf0, l15, kk, quad);
                a1[kk] = ldsA_r4(Hbf1, l15, kk, quad);
            }
            floatx4 ar = (floatx4)0.f, au = (floatx4)0.f;
            floatx4 a1r = (floatx4)0.f, a1u = (floatx4)0.f, axo = (floatx4)0.f;
            if (l0) {
#pragma unroll
                for (int kk = 0; kk < 4; ++kk) {
                    MFMA16(ar, a0[kk], B0r[kk]);
                    MFMA16(au, a0[kk], B0u[kk]);
                }
            }
            if (l1) {
#pragma unroll
                for (int kk = 0; kk < 4; ++kk) {
                    MFMA16(a1r, a0[kk], Bxr[kk]);
                    MFMA16(a1u, a0[kk], Bxu[kk]);
                    MFMA16(axo, a0[kk], Bxo[kk]);
                    MFMA16(a1r, a1[kk], B1r[kk]);
                    MFMA16(a1u, a1[kk], B1u[kk]);
                }
            }
            if (l0) {
                float rg = fast_sigmoid(ar[0] + xr);
                ug0s = fast_sigmoid(au[0] + xu);
                Rbf0[swi] = cvt_bf16(rg * h0s);
            }
            if (l1) {
                float rg1 = fast_sigmoid(a1r[0] + br1c);
                ug1s = fast_sigmoid(a1u[0] + bu1c);
                Rbf1[swi] = cvt_bf16(rg1 * h1s);
            }
            // publish monotone readiness (contiguous advance only)
            if (tid == 0 && tp < SEQ && pollv >= 6 && rdy_t == tp - 1) rdy_t = tp;
            sync_lds();

            // gated prefetch of xg(i+1) — fast path: fence only; slow: blocking wait
            float nr = 0.f, nu = 0.f, no = 0.f;
            if (pf) {
                if (rdy_t < i + 1) {
                    wait_ge(&cnt5[i + 1], 6);
                    if (tid == 0) rdy_t = i + 1;     // self-heal (all t<=i+1 now known ready)
                } else {
                    __builtin_amdgcn_fence(__ATOMIC_ACQUIRE, "agent");
                }
                nr = xgp[0];
                nu = xgp[512];
                no = xgp[1024];
                xgp += 1536;
            }

            // ---- Phase B: both o gates + both h updates
            floatx4 ao = (floatx4)0.f;
            if (l0) {
#pragma unroll
                for (int kk = 0; kk < 4; ++kk)
                    MFMA16(ao, ldsA_r4(Rbf0, l15, kk, quad), B0o[kk]);
            }
            if (l1) {
#pragma unroll
                for (int kk = 0; kk < 4; ++kk)
                    MFMA16(axo, ldsA_r4(Rbf1, l15, kk, quad), B1o[kk]);
            }
            if (l0) {
                float og = fast_tanh(ao[0] + xo);
                h0s = h0s + ug0s * (og - h0s);
                Hbf0[swi] = cvt_bf16(h0s);
            }
            if (l1) {
                float og1 = fast_tanh(axo[0] + bo1c);
                h1s = h1s + ug1s * (og1 - h1s);
                Hbf1[swi] = cvt_bf16(h1s);
            }
            if (pf) { xr = nr; xu = nu; xo = no; }
            sync_lds();
        }

        H1fin[(size_t)(b0 + quad) * HID + c] = h1s;
    }
}

// ---------------------------------------------------------------------------
// Classifier: out[b][c] = bfc[c] + sum_k H1[b][k] * Wfc[k][c]
// (also overwrites the counter scratch living at the head of d_out)
// ---------------------------------------------------------------------------
__global__ __launch_bounds__(256) void cls_kernel(
    const float* __restrict__ H1, const float* __restrict__ Wfc,
    const float* __restrict__ bfc, float* __restrict__ out)
{
    const int b = blockIdx.x;
    const int tid = threadIdx.x;
    __shared__ float h[HID];
    if (tid < HID) h[tid] = H1[(size_t)b * HID + tid];
    __syncthreads();
    for (int c = tid; c < NCLS; c += 256) {
        float a = bfc[c];
#pragma unroll 8
        for (int k = 0; k < HID; ++k)
            a += h[k] * Wfc[(size_t)k * NCLS + c];
        out[(size_t)b * NCLS + c] = a;
    }
}

// ---------------------------------------------------------------------------
extern "C" void kernel_launch(void* const* d_in, const int* in_sizes, int n_in,
                              void* d_out, int out_size, void* d_ws, size_t ws_size,
                              hipStream_t stream)
{
    const float* X   = (const float*)d_in[0];
    const float* Wr0 = (const float*)d_in[1];
    const float* br0 = (const float*)d_in[2];
    const float* Wu0 = (const float*)d_in[3];
    const float* bu0 = (const float*)d_in[4];
    const float* Wo0 = (const float*)d_in[5];
    const float* bo0 = (const float*)d_in[6];
    const float* Wr1 = (const float*)d_in[7];
    const float* br1 = (const float*)d_in[8];
    const float* Wu1 = (const float*)d_in[9];
    const float* bu1 = (const float*)d_in[10];
    const float* Wo1 = (const float*)d_in[11];
    const float* bo1 = (const float*)d_in[12];
    const float* Wfc = (const float*)d_in[13];
    const float* bfc = (const float*)d_in[14];
    float* out = (float*)d_out;

    // workspace:
    //   XG  fp32 [64][281][384][4]  110,493,696 B   (re-blocked for 64-block GRU)
    //   Abf bf16 [M_TOT*288]         41,435,136 B   (H1fin aliases: Abf dead after gemm)
    //   Wt0 bf16 [3*128*288]            221,184 B
    //   Wh0/Wx1/Wh1 bf16 [384*128]       98,304 B each
    // progress counters live in d_out[0..285] (ints), overwritten by cls.
    char* ws = (char*)d_ws;
    float*          XG    = (float*)ws;
    unsigned short* Abf   = (unsigned short*)(ws + (size_t)M_TOT * 384 * 4);
    float*          H1fin = (float*)Abf;        // alias: Abf dead after gemm phase
    unsigned short* Wt0   = (unsigned short*)(ws + (size_t)M_TOT * 384 * 4 + (size_t)M_TOT * KPAD0 * 2);
    unsigned short* Wh0   = Wt0 + (size_t)3 * HID * KPAD0;
    unsigned short* Wx1   = Wh0 + (size_t)384 * HID;
    unsigned short* Wh1   = Wx1 + (size_t)384 * HID;
    int*            cnt   = (int*)d_out;

    wt_kernel<<<dim3(12, 32), 256, 0, stream>>>(Wr0, Wu0, Wo0, Wr1, Wu1, Wo1,
                                                Wt0, Wh0, Wx1, Wh1, cnt);
    fused_all<<<dim3(256), 512, 0, stream>>>(X, Abf, Wt0, br0, bu0, bo0, XG,
                                             Wh0, Wx1, Wh1, br1, bu1, bo1, H1fin, cnt);
    cls_kernel<<<dim3(BATCH), 256, 0, stream>>>(H1fin, Wfc, bfc, out);
}

// Round 6
// 744.360 us; speedup vs baseline: 2.1248x; 2.1248x over previous
//
#include <hip/hip_runtime.h>
#include <math.h>

#define HID    128
#define IN_CH  271
#define SEQ    281
#define NCLS   1854
#define BATCH  256
#define M_TOT  (SEQ * BATCH)          // 71936
#define KPAD0  288                    // 271 padded to 9*32
#define NPROD  192                    // producer blocks; gru = blocks 192..255
#define XT_UNITS   1280               // (tb 0..4) x (b 0..255)
#define GEMM_UNITS 843                // 281 tt x 3 pair-units (each = 2 of 6 sub-units)

typedef __attribute__((ext_vector_type(8))) short short8;
typedef __attribute__((ext_vector_type(4))) float floatx4;

#define MFMA16(acc, a, b) acc = __builtin_amdgcn_mfma_f32_16x16x32_bf16((a), (b), (acc), 0, 0, 0)

__device__ __forceinline__ unsigned short f2bf(float f) {
    union { float f; unsigned u; } v; v.f = f;
    unsigned u = v.u;
    u += 0x7FFF + ((u >> 16) & 1);        // RNE
    return (unsigned short)(u >> 16);
}
__device__ __forceinline__ unsigned short cvt_bf16(float f) {
    unsigned r;
    asm("v_cvt_pk_bf16_f32 %0, %1, %1" : "=v"(r) : "v"(f));
    return (unsigned short)r;
}
__device__ __forceinline__ float fast_rcp(float x) {
    float r;
    asm("v_rcp_f32 %0, %1" : "=v"(r) : "v"(x));
    return r;
}
__device__ __forceinline__ float fast_sigmoid(float s) {
    return fast_rcp(1.f + __expf(-s));
}
__device__ __forceinline__ float fast_tanh(float s) {
    float e = __expf(-2.f * s);
    return __builtin_fmaf(2.f, fast_rcp(1.f + e), -1.f);
}
// LDS-only barrier: waits ds-ops but does NOT drain vmcnt.
__device__ __forceinline__ void sync_lds() {
    asm volatile("s_waitcnt lgkmcnt(0)\n\ts_barrier" ::: "memory");
}

// producer->consumer progress (cnt lives in d_out; cls overwrites it at the end)
//   cnt[0..4]  : xt units done per tb (target 256)
//   cnt[5+tt]  : gemm sub-units done for step tt (target 6)
// R5 post-mortem: agent-ACQUIRE spins by all 512 threads emitted buffer_inv
// (XCD L2 invalidate) per poll -> chip-wide coherence storm (5x slowdown).
// R6: relaxed (sc1, no invalidate) polls by tid0 only; data reads use
// relaxed-agent atomic loads (bypass L1/L2 -> read coherence point) so NO
// acquire is ever needed on the consumer fast path.
__device__ __forceinline__ int relaxed_peek(int* p) {
    return __hip_atomic_load(p, __ATOMIC_RELAXED, __HIP_MEMORY_SCOPE_AGENT);
}
__device__ __forceinline__ void spin_relaxed(int* p, int tgt) {
    while (relaxed_peek(p) < tgt) __builtin_amdgcn_s_sleep(8);
}
__device__ __forceinline__ void release_add(int* p, int v) {
    __hip_atomic_fetch_add(p, v, __ATOMIC_RELEASE, __HIP_MEMORY_SCOPE_AGENT);
}
__device__ __forceinline__ float aload_f(const float* p) {
    return __hip_atomic_load(p, __ATOMIC_RELAXED, __HIP_MEMORY_SCOPE_AGENT);
}

// ---------------------------------------------------------------------------
// 4-row swizzled LDS h-tile (R2-verified: SQ_LDS_BANK_CONFLICT = 0):
//   element (row, k) at  row*128 + (((k>>3) ^ (2*row)) << 3) + (k&7)
// ---------------------------------------------------------------------------
__device__ __forceinline__ short8 ldsA_r4(const unsigned short* base, int l15, int kk, int quad) {
    const int row4  = l15 >> 2;
    const int chunk = (4 * kk + quad) ^ (row4 << 1);
    return *(const short8*)(base + row4 * 128 + (chunk << 3));
}
__device__ __forceinline__ int sw_idx4(int row, int c) {
    return row * 128 + ((((c >> 3) ^ (row << 1)) << 3) | (c & 7));
}

// ---------------------------------------------------------------------------
// Weight transpose+convert (unchanged) + zeroing of the progress counters.
// Runs before the fused kernel; dispatch boundary gives full coherence.
// ---------------------------------------------------------------------------
__global__ __launch_bounds__(256) void wt_kernel(
    const float* __restrict__ Wr0, const float* __restrict__ Wu0, const float* __restrict__ Wo0,
    const float* __restrict__ Wr1, const float* __restrict__ Wu1, const float* __restrict__ Wo1,
    unsigned short* __restrict__ Wt0, unsigned short* __restrict__ Wh0,
    unsigned short* __restrict__ Wx1, unsigned short* __restrict__ Wh1,
    int* __restrict__ cnt)
{
    const int blk  = blockIdx.x;
    const int kind = blk / 3, g = blk % 3;
    const int tid  = threadIdx.x;
    const int n0   = blockIdx.y * 4;

    if (blk == 0 && blockIdx.y == 0)
        for (int j = tid; j < 5 + SEQ; j += 256) cnt[j] = 0;

    const float* __restrict__ W =
        (kind <= 1) ? ((g == 0) ? Wr0 : (g == 1) ? Wu0 : Wo0)
                    : ((g == 0) ? Wr1 : (g == 1) ? Wu1 : Wo1);

    if (kind == 0) {
        unsigned short* __restrict__ out = Wt0 + (size_t)g * HID * KPAD0;
        for (int n = n0; n < n0 + 4; ++n)
            for (int k = tid; k < KPAD0; k += 256) {
                float v = (k < IN_CH) ? W[(size_t)k * HID + n] : 0.f;
                out[(size_t)n * KPAD0 + k] = f2bf(v);
            }
    } else {
        const int rbase = (kind == 1) ? IN_CH : (kind == 2) ? 0 : HID;
        unsigned short* __restrict__ out =
            ((kind == 1) ? Wh0 : (kind == 2) ? Wx1 : Wh1) + (size_t)g * HID * HID;
        for (int n = n0; n < n0 + 4; ++n)
            for (int k = tid; k < HID; k += 256)
                out[(size_t)n * HID + k] = f2bf(W[(size_t)(rbase + k) * HID + n]);
    }
}

// ---------------------------------------------------------------------------
// FUSED pipeline kernel: 256 blocks x 512 threads, 1 block/CU (full reg file).
//   blocks 0..191  : PRODUCERS — xt (X transpose->bf16) then gemm (x-gates).
//   blocks 192..255: CONSUMERS — the R2 skewed 2-phase GRU, gated per-t.
// Producer order: xt tb=0 -> gemm tt<64 -> xt rest -> gemm rest (64-step
// runway for the GRU).  Visibility: producers release-add (wbl2 -> L3)
// after __syncthreads; consumers read flags AND XG with relaxed-agent
// atomic loads (sc0/sc1: bypass L1/L2, read the coherence point) — zero
// cache-invalidates in the steady state.  Producer-side Abf reads keep one
// tid0 acquire-fence per gemm unit (843 total, harmless).
// ---------------------------------------------------------------------------
__global__ __launch_bounds__(512, 2) void fused_all(
    const float* __restrict__ X,
    unsigned short* __restrict__ Abf,
    const unsigned short* __restrict__ Wt0,
    const float* __restrict__ br0, const float* __restrict__ bu0, const float* __restrict__ bo0,
    float* __restrict__ XG,
    const unsigned short* __restrict__ Wh0,
    const unsigned short* __restrict__ Wx1,
    const unsigned short* __restrict__ Wh1,
    const float* __restrict__ br1, const float* __restrict__ bu1, const float* __restrict__ bo1,
    float* __restrict__ H1fin,
    int* __restrict__ cnt)
{
    __shared__ __attribute__((aligned(16))) char smem[40960];
    __shared__ int rdy_t;
    const int bid = blockIdx.x;
    const int tid = threadIdx.x;

    if (bid < NPROD) {
        // =================== PRODUCER ===================
        const int pid = bid;

        // tid0-only relaxed spin, one acquire fence (L1/L2 inv) per wait
        auto block_wait = [&](int* p, int tgt) {
            if (tid == 0) {
                spin_relaxed(p, tgt);
                __builtin_amdgcn_fence(__ATOMIC_ACQUIRE, "agent");
            }
            __syncthreads();
        };

        // ---- xt unit: transpose+convert X[b][k][t0..t0+63] -> Abf
        auto xt_unit = [&](int u) {
            const int tb = u >> 8, b = u & 255;
            const int t0 = tb * 64;
            const float* Xb = X + (size_t)b * (IN_CH * SEQ);
            float (*Xl)[65] = (float (*)[65])smem;
            for (int kc = 0; kc < KPAD0 / 32; ++kc) {
#pragma unroll
                for (int r = 0; r < 4; ++r) {
                    int e = tid + 512 * r;
                    int kk = e >> 6, tt = e & 63;
                    int k = kc * 32 + kk, t = t0 + tt;
                    Xl[kk][tt] = (k < IN_CH && t < SEQ) ? Xb[k * SEQ + t] : 0.f;
                }
                __syncthreads();
                if (tid < 256) {
                    int tt = tid >> 2, part = tid & 3, t = t0 + tt;
                    if (t < SEQ) {
                        union { unsigned short s[8]; uint4 v; } uu;
#pragma unroll
                        for (int i2 = 0; i2 < 8; ++i2) uu.s[i2] = f2bf(Xl[part * 8 + i2][tt]);
                        *(uint4*)(Abf + ((size_t)b * SEQ + t) * KPAD0 + kc * 32 + part * 8) = uu.v;
                    }
                }
                __syncthreads();
            }
            if (tid == 0) release_add(&cnt[tb], 1);
        };

        // ---- gemm pair-unit: 512 thr = two independent 256-thr sub-units.
        const int half = tid >> 8, t2 = tid & 255;
        unsigned short* As = (unsigned short*)(smem + half * 20480);
        unsigned short* Bs = As + 5120;
        const int lane  = t2 & 63;
        const int wave  = t2 >> 6;
        const int l15   = lane & 15;
        const int quad  = lane >> 4;
        const int mhalf = wave >> 1;
        const int nhalf = wave & 1;
        const int r0 = t2 >> 2, p0 = t2 & 3;
        const int r1 = r0 + 64;

        auto gemm_unit = [&](int p) {
            const int tt  = p / 3;
            const int s   = (p % 3) * 2 + half;
            const int g   = s >> 1;
            const int b0m = (s & 1) * 128;
            const unsigned short* Bw = Wt0 + (size_t)g * HID * KPAD0;
            const float* bias = (g == 0) ? br0 : (g == 1) ? bu0 : bo0;

            block_wait(&cnt[tt >> 6], 256);          // A rows (.,tt) need xt tb done

            floatx4 acc[4][4];
#pragma unroll
            for (int im = 0; im < 4; ++im)
#pragma unroll
                for (int in = 0; in < 4; ++in) acc[im][in] = (floatx4)0.f;

            for (int kt = 0; kt < KPAD0 / 32; ++kt) {
                __syncthreads();                     // guards As/Bs reuse
                const int kb = kt * 32;
                uint4 va0 = *(const uint4*)(Abf + ((size_t)(b0m + r0) * SEQ + tt) * KPAD0 + kb + p0 * 8);
                uint4 va1 = *(const uint4*)(Abf + ((size_t)(b0m + r1) * SEQ + tt) * KPAD0 + kb + p0 * 8);
                uint4 vb0 = *(const uint4*)(Bw + (size_t)r0 * KPAD0 + kb + p0 * 8);
                uint4 vb1 = *(const uint4*)(Bw + (size_t)r1 * KPAD0 + kb + p0 * 8);
                *(uint4*)(As + r0 * 40 + p0 * 8) = va0;
                *(uint4*)(As + r1 * 40 + p0 * 8) = va1;
                *(uint4*)(Bs + r0 * 40 + p0 * 8) = vb0;
                *(uint4*)(Bs + r1 * 40 + p0 * 8) = vb1;
                __syncthreads();

                short8 bf[4];
#pragma unroll
                for (int in = 0; in < 4; ++in)
                    bf[in] = *(const short8*)(Bs + (nhalf * 64 + in * 16 + l15) * 40 + quad * 8);
#pragma unroll
                for (int im = 0; im < 4; ++im) {
                    short8 af = *(const short8*)(As + (mhalf * 64 + im * 16 + l15) * 40 + quad * 8);
#pragma unroll
                    for (int in = 0; in < 4; ++in)
                        MFMA16(acc[im][in], af, bf[in]);
                }
            }

            float bv[4];
#pragma unroll
            for (int in = 0; in < 4; ++in) bv[in] = bias[nhalf * 64 + in * 16 + l15];
#pragma unroll
            for (int im = 0; im < 4; ++im) {
                const int bb = b0m + mhalf * 64 + im * 16 + quad * 4;
#pragma unroll
                for (int in = 0; in < 4; ++in) {
                    const int n = nhalf * 64 + in * 16 + l15;
                    float4 v = make_float4(acc[im][in][0] + bv[in], acc[im][in][1] + bv[in],
                                           acc[im][in][2] + bv[in], acc[im][in][3] + bv[in]);
                    float* dst = XG + ((size_t)(bb >> 2) * SEQ + tt) * 1536 + ((size_t)g * HID + n) * 4;
                    *(float4*)dst = v;
                }
            }
            __syncthreads();
            if (tid == 0) release_add(&cnt[5 + tt], 2);
        };

        // ---- 4-phase order: tb=0 first, then gemm tt<64, then the rest
        for (int u = pid; u < 256; u += NPROD)        xt_unit(u);
        for (int p = pid; p < NPROD; p += NPROD)      gemm_unit(p);   // tt 0..63
        for (int u = 256 + pid; u < XT_UNITS; u += NPROD)   xt_unit(u);
        for (int p = NPROD + pid; p < GEMM_UNITS; p += NPROD) gemm_unit(p);

    } else {
        // =================== GRU CONSUMER ===================
        const int gb   = bid - NPROD;     // 0..63
        const int b0   = gb * 4;
        const int w    = tid >> 6;
        const int lane = tid & 63;
        const int l15  = lane & 15;
        const int quad = lane >> 4;       // this lane's batch row 0..3
        const int c    = w * 16 + l15;    // this lane's column 0..127

        unsigned short* Hbf0 = (unsigned short*)smem;
        unsigned short* Rbf0 = Hbf0 + 512;
        unsigned short* Hbf1 = Hbf0 + 1024;
        unsigned short* Rbf1 = Hbf0 + 1536;
        int* cnt5 = cnt + 5;

        // hoisted weight B-fragments: 9 (layer,gate) tiles x 4 k-steps (AGPRs)
        short8 B0r[4], B0u[4], B0o[4], Bxr[4], Bxu[4], Bxo[4], B1r[4], B1u[4], B1o[4];
#pragma unroll
        for (int kk = 0; kk < 4; ++kk) {
            const size_t off = (size_t)c * HID + kk * 32 + quad * 8;
            B0r[kk] = *(const short8*)(Wh0 + off);
            B0u[kk] = *(const short8*)(Wh0 + (size_t)128 * HID + off);
            B0o[kk] = *(const short8*)(Wh0 + (size_t)256 * HID + off);
            Bxr[kk] = *(const short8*)(Wx1 + off);
            Bxu[kk] = *(const short8*)(Wx1 + (size_t)128 * HID + off);
            Bxo[kk] = *(const short8*)(Wx1 + (size_t)256 * HID + off);
            B1r[kk] = *(const short8*)(Wh1 + off);
            B1u[kk] = *(const short8*)(Wh1 + (size_t)128 * HID + off);
            B1o[kk] = *(const short8*)(Wh1 + (size_t)256 * HID + off);
        }
        Hbf0[tid] = 0; Rbf0[tid] = 0; Hbf1[tid] = 0; Rbf1[tid] = 0;

        float h0s = 0.f, h1s = 0.f, ug0s = 0.f, ug1s = 0.f;
        const float br1c = br1[c], bu1c = bu1[c], bo1c = bo1[c];
        const int swi = sw_idx4(quad, c);

        // prime: t=0,1 ready (tid0 relaxed spin only — no invalidates)
        if (tid == 0) {
            spin_relaxed(&cnt5[0], 6);
            spin_relaxed(&cnt5[1], 6);
            rdy_t = 1;
        }
        __syncthreads();                  // covers LDS zero-init + rdy_t
        int rdy_reg = 1;                  // tid0's private mirror of rdy_t

        const float* xgp = XG + (size_t)gb * SEQ * 1536 + (size_t)c * 4 + quad;
        asm volatile("" ::: "memory");
        float xr = aload_f(xgp);
        float xu = aload_f(xgp + 512);
        float xo = aload_f(xgp + 1024);
        xgp += 1536;

        for (int i = 0; i <= SEQ; ++i) {
            const bool l0 = (i < SEQ);
            const bool l1 = (i > 0);
            const bool pf = (i + 1 < SEQ);

            // relaxed poll of the NEXT unpublished step (latency hides under Phase A)
            bool adv = false;
            if (tid == 0 && rdy_reg + 1 < SEQ)
                adv = (relaxed_peek(&cnt5[rdy_reg + 1]) >= 6);

            // ---- Phase A: read h0(i-1)/h1(i-2) once; all r,u gates + L1 o-x part
            short8 a0[4], a1[4];
#pragma unroll
            for (int kk = 0; kk < 4; ++kk) {
                a0[kk] = ldsA_r4(Hbf0, l15, kk, quad);
                a1[kk] = ldsA_r4(Hbf1, l15, kk, quad);
            }
            floatx4 ar = (floatx4)0.f, au = (floatx4)0.f;
            floatx4 a1r = (floatx4)0.f, a1u = (floatx4)0.f, axo = (floatx4)0.f;
            if (l0) {
#pragma unroll
                for (int kk = 0; kk < 4; ++kk) {
                    MFMA16(ar, a0[kk], B0r[kk]);
                    MFMA16(au, a0[kk], B0u[kk]);
                }
            }
            if (l1) {
#pragma unroll
                for (int kk = 0; kk < 4; ++kk) {
                    MFMA16(a1r, a0[kk], Bxr[kk]);
                    MFMA16(a1u, a0[kk], Bxu[kk]);
                    MFMA16(axo, a0[kk], Bxo[kk]);
                    MFMA16(a1r, a1[kk], B1r[kk]);
                    MFMA16(a1u, a1[kk], B1u[kk]);
                }
            }
            if (l0) {
                float rg = fast_sigmoid(ar[0] + xr);
                ug0s = fast_sigmoid(au[0] + xu);
                Rbf0[swi] = cvt_bf16(rg * h0s);
            }
            if (l1) {
                float rg1 = fast_sigmoid(a1r[0] + br1c);
                ug1s = fast_sigmoid(a1u[0] + bu1c);
                Rbf1[swi] = cvt_bf16(rg1 * h1s);
            }
            if (tid == 0 && adv) { rdy_reg += 1; rdy_t = rdy_reg; }
            sync_lds();

            // gated prefetch of xg(i+1): fast path has ZERO sync cost
            float nr = 0.f, nu = 0.f, no = 0.f;
            if (pf) {
                if (rdy_t < i + 1) {                 // uniform (LDS, post-barrier)
                    if (tid == 0) {
                        spin_relaxed(&cnt5[i + 1], 6);
                        rdy_reg = i + 1;
                        rdy_t = i + 1;               // self-heal, stays contiguous
                    }
                    sync_lds();
                }
                asm volatile("" ::: "memory");       // no hoisting loads above gate
                nr = aload_f(xgp);
                nu = aload_f(xgp + 512);
                no = aload_f(xgp + 1024);
                xgp += 1536;
            }

            // ---- Phase B: both o gates + both h updates
            floatx4 ao = (floatx4)0.f;
            if (l0) {
#pragma unroll
                for (int kk = 0; kk < 4; ++kk)
                    MFMA16(ao, ldsA_r4(Rbf0, l15, kk, quad), B0o[kk]);
            }
            if (l1) {
#pragma unroll
                for (int kk = 0; kk < 4; ++kk)
                    MFMA16(axo, ldsA_r4(Rbf1, l15, kk, quad), B1o[kk]);
            }
            if (l0) {
                float og = fast_tanh(ao[0] + xo);
                h0s = h0s + ug0s * (og - h0s);
                Hbf0[swi] = cvt_bf16(h0s);
            }
            if (l1) {
                float og1 = fast_tanh(axo[0] + bo1c);
                h1s = h1s + ug1s * (og1 - h1s);
                Hbf1[swi] = cvt_bf16(h1s);
            }
            if (pf) { xr = nr; xu = nu; xo = no; }
            sync_lds();
        }

        H1fin[(size_t)(b0 + quad) * HID + c] = h1s;
    }
}

// ---------------------------------------------------------------------------
// Classifier: out[b][c] = bfc[c] + sum_k H1[b][k] * Wfc[k][c]
// (also overwrites the counter scratch living at the head of d_out)
// ---------------------------------------------------------------------------
__global__ __launch_bounds__(256) void cls_kernel(
    const float* __restrict__ H1, const float* __restrict__ Wfc,
    const float* __restrict__ bfc, float* __restrict__ out)
{
    const int b = blockIdx.x;
    const int tid = threadIdx.x;
    __shared__ float h[HID];
    if (tid < HID) h[tid] = H1[(size_t)b * HID + tid];
    __syncthreads();
    for (int c = tid; c < NCLS; c += 256) {
        float a = bfc[c];
#pragma unroll 8
        for (int k = 0; k < HID; ++k)
            a += h[k] * Wfc[(size_t)k * NCLS + c];
        out[(size_t)b * NCLS + c] = a;
    }
}

// ---------------------------------------------------------------------------
extern "C" void kernel_launch(void* const* d_in, const int* in_sizes, int n_in,
                              void* d_out, int out_size, void* d_ws, size_t ws_size,
                              hipStream_t stream)
{
    const float* X   = (const float*)d_in[0];
    const float* Wr0 = (const float*)d_in[1];
    const float* br0 = (const float*)d_in[2];
    const float* Wu0 = (const float*)d_in[3];
    const float* bu0 = (const float*)d_in[4];
    const float* Wo0 = (const float*)d_in[5];
    const float* bo0 = (const float*)d_in[6];
    const float* Wr1 = (const float*)d_in[7];
    const float* br1 = (const float*)d_in[8];
    const float* Wu1 = (const float*)d_in[9];
    const float* bu1 = (const float*)d_in[10];
    const float* Wo1 = (const float*)d_in[11];
    const float* bo1 = (const float*)d_in[12];
    const float* Wfc = (const float*)d_in[13];
    const float* bfc = (const float*)d_in[14];
    float* out = (float*)d_out;

    // workspace:
    //   XG  fp32 [64][281][384][4]  110,493,696 B   (re-blocked for 64-block GRU)
    //   Abf bf16 [M_TOT*288]         41,435,136 B   (H1fin aliases: Abf dead after gemm)
    //   Wt0 bf16 [3*128*288]            221,184 B
    //   Wh0/Wx1/Wh1 bf16 [384*128]       98,304 B each
    // progress counters live in d_out[0..285] (ints), overwritten by cls.
    char* ws = (char*)d_ws;
    float*          XG    = (float*)ws;
    unsigned short* Abf   = (unsigned short*)(ws + (size_t)M_TOT * 384 * 4);
    float*          H1fin = (float*)Abf;        // alias: Abf dead after gemm phase
    unsigned short* Wt0   = (unsigned short*)(ws + (size_t)M_TOT * 384 * 4 + (size_t)M_TOT * KPAD0 * 2);
    unsigned short* Wh0   = Wt0 + (size_t)3 * HID * KPAD0;
    unsigned short* Wx1   = Wh0 + (size_t)384 * HID;
    unsigned short* Wh1   = Wx1 + (size_t)384 * HID;
    int*            cnt   = (int*)d_out;

    wt_kernel<<<dim3(12, 32), 256, 0, stream>>>(Wr0, Wu0, Wo0, Wr1, Wu1, Wo1,
                                                Wt0, Wh0, Wx1, Wh1, cnt);
    fused_all<<<dim3(256), 512, 0, stream>>>(X, Abf, Wt0, br0, bu0, bo0, XG,
                                             Wh0, Wx1, Wh1, br1, bu1, bo1, H1fin, cnt);
    cls_kernel<<<dim3(BATCH), 256, 0, stream>>>(H1fin, Wfc, bfc, out);
}

// Round 7
// 572.849 us; speedup vs baseline: 2.7610x; 1.2994x over previous
//
#include <hip/hip_runtime.h>
#include <math.h>

#define HID    128
#define IN_CH  271
#define SEQ    281
#define NCLS   1854
#define BATCH  256
#define KPAD0  288                    // 271 padded to 9*32

typedef __attribute__((ext_vector_type(8))) short short8;
typedef __attribute__((ext_vector_type(4))) float floatx4;

#define MFMA16(acc, a, b) acc = __builtin_amdgcn_mfma_f32_16x16x32_bf16((a), (b), (acc), 0, 0, 0)

__device__ __forceinline__ unsigned short f2bf(float f) {
    union { float f; unsigned u; } v; v.f = f;
    unsigned u = v.u;
    u += 0x7FFF + ((u >> 16) & 1);        // RNE
    return (unsigned short)(u >> 16);
}
// single-instruction bf16 convert (RNE, bit-identical to f2bf for finite vals)
__device__ __forceinline__ unsigned short cvt_bf16(float f) {
    unsigned r;
    asm("v_cvt_pk_bf16_f32 %0, %1, %1" : "=v"(r) : "v"(f));
    return (unsigned short)r;
}
__device__ __forceinline__ float fast_rcp(float x) {
    float r;
    asm("v_rcp_f32 %0, %1" : "=v"(r) : "v"(x));
    return r;
}
__device__ __forceinline__ float fast_sigmoid(float s) {
    return fast_rcp(1.f + __expf(-s));
}
// tanh(x) = 2/(1+e^{-2x}) - 1 ; exp limits give exactly -1/+1, branch-free
__device__ __forceinline__ float fast_tanh(float s) {
    float e = __expf(-2.f * s);
    return __builtin_fmaf(2.f, fast_rcp(1.f + e), -1.f);
}
// LDS-only barrier: waits ds-ops but does NOT drain vmcnt.
__device__ __forceinline__ void sync_lds() {
    asm volatile("s_waitcnt lgkmcnt(0)\n\ts_barrier" ::: "memory");
}

// ---------------------------------------------------------------------------
// 4-row swizzled LDS h-tile (R2-verified: SQ_LDS_BANK_CONFLICT = 0):
//   element (row, k) at  row*128 + (((k>>3) ^ (2*row)) << 3) + (k&7)
// ---------------------------------------------------------------------------
__device__ __forceinline__ short8 ldsA_r4(const unsigned short* base, int l15, int kk, int quad) {
    const int row4  = l15 >> 2;
    const int chunk = (4 * kk + quad) ^ (row4 << 1);
    return *(const short8*)(base + row4 * 128 + (chunk << 3));
}
__device__ __forceinline__ int sw_idx4(int row, int c) {
    return row * 128 + ((((c >> 3) ^ (row << 1)) << 3) | (c & 7));
}

// ---------------------------------------------------------------------------
// Weight transpose+convert. grid (12, 32), blockIdx.y = n-slice of 4.
// blk 0..2 : Wt0 [n][288]        = W0g[k][n], k<271, zero-padded (gemm A)
// blk 3..5 : Wh0 [g*128+n][128]  = W0g[271+k][n]     (gru, layer0 h-part)
// blk 6..8 : Wx1 [g*128+n][128]  = W1g[k][n]         (gru, layer1 x-part)
// blk 9..11: Wh1 [g*128+n][128]  = W1g[128+k][n]     (gru, layer1 h-part)
// ---------------------------------------------------------------------------
__global__ __launch_bounds__(256) void wt_kernel(
    const float* __restrict__ Wr0, const float* __restrict__ Wu0, const float* __restrict__ Wo0,
    const float* __restrict__ Wr1, const float* __restrict__ Wu1, const float* __restrict__ Wo1,
    unsigned short* __restrict__ Wt0, unsigned short* __restrict__ Wh0,
    unsigned short* __restrict__ Wx1, unsigned short* __restrict__ Wh1)
{
    const int blk  = blockIdx.x;
    const int kind = blk / 3, g = blk % 3;
    const int tid  = threadIdx.x;
    const int n0   = blockIdx.y * 4;

    const float* __restrict__ W =
        (kind <= 1) ? ((g == 0) ? Wr0 : (g == 1) ? Wu0 : Wo0)
                    : ((g == 0) ? Wr1 : (g == 1) ? Wu1 : Wo1);

    if (kind == 0) {
        unsigned short* __restrict__ out = Wt0 + (size_t)g * HID * KPAD0;
        for (int n = n0; n < n0 + 4; ++n)
            for (int k = tid; k < KPAD0; k += 256) {
                float v = (k < IN_CH) ? W[(size_t)k * HID + n] : 0.f;
                out[(size_t)n * KPAD0 + k] = f2bf(v);
            }
    } else {
        const int rbase = (kind == 1) ? IN_CH : (kind == 2) ? 0 : HID;
        unsigned short* __restrict__ out =
            ((kind == 1) ? Wh0 : (kind == 2) ? Wx1 : Wh1) + (size_t)g * HID * HID;
        for (int n = n0; n < n0 + 4; ++n)
            for (int k = tid; k < HID; k += 256)
                out[(size_t)n * HID + k] = f2bf(W[(size_t)(rbase + k) * HID + n]);
    }
}

// ---------------------------------------------------------------------------
// gemm_bx — R7: xt + gemm_xg fused; Abf eliminated.
//   C_b[n][t] = sum_k Wt0[n][k] * X[b][k][t]   (bias folded into GRU)
// A = Wt0 [384 n][288 k] (k-contiguous, L2-resident ~221 KB; frags loaded
// per k-step from global).  B = X_b [k][t] (t-contiguous rows): staged per
// k-step through LDS: coalesced fp32 loads -> Xl[32][65] -> transpose+cvt ->
// Bt[64 t][40-stride k] bf16 (stride 40: 2-way banks, free; xt's inner loop
// kept LDS-resident instead of an HBM round trip).
// Block = (b, t-tile of 64), 256 thr, computes all 384 n.  Wave (mh,nh):
// 192 n x 32 t = 12x2 MFMA tiles, 9 k-steps -> 216 MFMA/wave.
// Output: XG[b>>2][t][b&3][chan] fp32 — per (b,t) the block writes 384
// consecutive floats (full-line dirty, no RMW); float4 per tile-reg row.
// ---------------------------------------------------------------------------
__global__ __launch_bounds__(256) void gemm_bx(
    const float* __restrict__ X,
    const unsigned short* __restrict__ Wt0,
    float* __restrict__ XG)
{
    const int b   = blockIdx.x;
    const int t0  = blockIdx.y * 64;
    const int tid = threadIdx.x;

    __shared__ float Xl[32][65];
    __shared__ unsigned short Bt[64 * 40];

    const int lane  = tid & 63;
    const int wave  = tid >> 6;
    const int l15   = lane & 15;
    const int quad  = lane >> 4;
    const int mhalf = wave >> 1;          // n-half: 192 rows
    const int nhalf = wave & 1;           // t-half: 32 cols

    const float* __restrict__ Xb = X + (size_t)b * (IN_CH * SEQ);

    floatx4 acc[12][2];
#pragma unroll
    for (int it = 0; it < 12; ++it) {
        acc[it][0] = (floatx4)0.f;
        acc[it][1] = (floatx4)0.f;
    }

    const int tt_s = tid >> 2, part = tid & 3;    // transpose roles

    for (int kt = 0; kt < 9; ++kt) {
        const int kb = kt * 32;

        // A-frags for this k-step (L2-hit after first block per XCD)
        short8 af[12];
#pragma unroll
        for (int it = 0; it < 12; ++it) {
            const int n = mhalf * 192 + it * 16 + l15;
            af[it] = *(const short8*)(Wt0 + (size_t)n * KPAD0 + kb + quad * 8);
        }

        // stage X[b][kb..kb+31][t0..t0+63] -> Xl (coalesced 256B rows)
#pragma unroll
        for (int r = 0; r < 8; ++r) {
            int e = tid + 256 * r;
            int kk = e >> 6, tt = e & 63;
            int k = kb + kk, t = t0 + tt;
            Xl[kk][tt] = (k < IN_CH && t < SEQ) ? Xb[k * SEQ + t] : 0.f;
        }
        __syncthreads();

        // transpose+convert: Bt[tt][part*8..+8) bf16  (uint4 store, stride 40)
        {
            union { unsigned short s[8]; uint4 v; } u;
#pragma unroll
            for (int i2 = 0; i2 < 8; ++i2) u.s[i2] = f2bf(Xl[part * 8 + i2][tt_s]);
            *(uint4*)(Bt + tt_s * 40 + part * 8) = u.v;
        }
        __syncthreads();

        // MFMA: 12 n-tiles x 2 t-tiles
        short8 bf[2];
#pragma unroll
        for (int jt = 0; jt < 2; ++jt)
            bf[jt] = *(const short8*)(Bt + (nhalf * 32 + jt * 16 + l15) * 40 + quad * 8);
#pragma unroll
        for (int it = 0; it < 12; ++it) {
#pragma unroll
            for (int jt = 0; jt < 2; ++jt)
                MFMA16(acc[it][jt], af[it], bf[jt]);
        }
    }

    // epilogue: D(row = n = base+quad*4+j, col = t = base+l15)
    const size_t bg_base = ((size_t)(b >> 2) * SEQ) * 1536 + (size_t)(b & 3) * 384;
#pragma unroll
    for (int jt = 0; jt < 2; ++jt) {
        const int t = t0 + nhalf * 32 + jt * 16 + l15;
        if (t < SEQ) {
            const size_t trow = bg_base + (size_t)t * 1536;
#pragma unroll
            for (int it = 0; it < 12; ++it) {
                const int n = mhalf * 192 + it * 16 + quad * 4;
                *(float4*)(XG + trow + n) = *(float4*)&acc[it][jt];
            }
        }
    }
}

// ---------------------------------------------------------------------------
// FUSED 2-layer GRU — 64 blocks x 4 batch rows, skewed 2-phase pipeline.
// R2-proven body (266 us, conflicts = 0).  Changes for R7: XG layout
// [b>>2][t][b&3][chan] (coalescing identical: 4 x 64B segments/wave) and
// layer-0 bias folded here (gemm stores raw acc): +3 const VGPRs.
// Keep arch VGPR <= ~140 (unified 256/wave cliff).
// ---------------------------------------------------------------------------
__global__ __launch_bounds__(512, 1) void gru_fused(
    const unsigned short* __restrict__ Wh0,
    const unsigned short* __restrict__ Wx1,
    const unsigned short* __restrict__ Wh1,
    const float* __restrict__ XG,
    const float* __restrict__ br0, const float* __restrict__ bu0, const float* __restrict__ bo0,
    const float* __restrict__ br1, const float* __restrict__ bu1, const float* __restrict__ bo1,
    float* __restrict__ H1fin)
{
    const int b0   = blockIdx.x * 4;
    const int tid  = threadIdx.x;
    const int w    = tid >> 6;        // 0..7
    const int lane = tid & 63;
    const int l15  = lane & 15;
    const int quad = lane >> 4;       // this lane's batch row 0..3
    const int c    = w * 16 + l15;    // this lane's column 0..127

    __shared__ __attribute__((aligned(16))) unsigned short Hbf0[4 * 128];
    __shared__ __attribute__((aligned(16))) unsigned short Rbf0[4 * 128];
    __shared__ __attribute__((aligned(16))) unsigned short Hbf1[4 * 128];
    __shared__ __attribute__((aligned(16))) unsigned short Rbf1[4 * 128];

    // hoisted weight B-fragments: 9 (layer,gate) tiles x 4 k-steps
    short8 B0r[4], B0u[4], B0o[4], Bxr[4], Bxu[4], Bxo[4], B1r[4], B1u[4], B1o[4];
#pragma unroll
    for (int kk = 0; kk < 4; ++kk) {
        const size_t off = (size_t)c * HID + kk * 32 + quad * 8;
        B0r[kk] = *(const short8*)(Wh0 + off);
        B0u[kk] = *(const short8*)(Wh0 + (size_t)128 * HID + off);
        B0o[kk] = *(const short8*)(Wh0 + (size_t)256 * HID + off);
        Bxr[kk] = *(const short8*)(Wx1 + off);
        Bxu[kk] = *(const short8*)(Wx1 + (size_t)128 * HID + off);
        Bxo[kk] = *(const short8*)(Wx1 + (size_t)256 * HID + off);
        B1r[kk] = *(const short8*)(Wh1 + off);
        B1u[kk] = *(const short8*)(Wh1 + (size_t)128 * HID + off);
        B1o[kk] = *(const short8*)(Wh1 + (size_t)256 * HID + off);
    }

    for (int idx = tid; idx < 4 * 128; idx += 512) {
        Hbf0[idx] = 0; Rbf0[idx] = 0; Hbf1[idx] = 0; Rbf1[idx] = 0;
    }

    float h0s = 0.f, h1s = 0.f, ug0s = 0.f, ug1s = 0.f;

    const float b0r_c = br0[c], b0u_c = bu0[c], b0o_c = bo0[c];
    const float br1c = br1[c], bu1c = bu1[c], bo1c = bo1[c];

    // swizzled write index for this lane's single cell (row=quad, col=c)
    const int swi = sw_idx4(quad, c);

    // XG [gb][t][r=quad][chan]: lane reads chan=c (+128,+256)
    const float* xgp = XG + (size_t)blockIdx.x * SEQ * 1536 + quad * 384 + c;
    float xr = xgp[0];
    float xu = xgp[128];
    float xo = xgp[256];
    xgp += 1536;
    __syncthreads();

    for (int i = 0; i <= SEQ; ++i) {
        const bool l0 = (i < SEQ);     // layer 0 computes step i
        const bool l1 = (i > 0);       // layer 1 computes step i-1

        // prefetch xg(i+1) — lands during this step's compute
        float nr, nu, no;
        const bool pf = (i + 1 < SEQ);
        if (pf) {
            nr = xgp[0];
            nu = xgp[128];
            no = xgp[256];
            xgp += 1536;
        }

        // ---- Phase A: single read of h0(i-1)/h1(i-2); all r,u gates + L1 o-x part
        short8 a0[4], a1[4];
#pragma unroll
        for (int kk = 0; kk < 4; ++kk) {
            a0[kk] = ldsA_r4(Hbf0, l15, kk, quad);
            a1[kk] = ldsA_r4(Hbf1, l15, kk, quad);
        }
        floatx4 ar = (floatx4)0.f, au = (floatx4)0.f;
        floatx4 a1r = (floatx4)0.f, a1u = (floatx4)0.f, axo = (floatx4)0.f;
        if (l0) {
#pragma unroll
            for (int kk = 0; kk < 4; ++kk) {
                MFMA16(ar, a0[kk], B0r[kk]);
                MFMA16(au, a0[kk], B0u[kk]);
            }
        }
        if (l1) {
#pragma unroll
            for (int kk = 0; kk < 4; ++kk) {
                MFMA16(a1r, a0[kk], Bxr[kk]);
                MFMA16(a1u, a0[kk], Bxu[kk]);
                MFMA16(axo, a0[kk], Bxo[kk]);
                MFMA16(a1r, a1[kk], B1r[kk]);
                MFMA16(a1u, a1[kk], B1u[kk]);
            }
        }
        if (l0) {
            float rg = fast_sigmoid(ar[0] + xr + b0r_c);
            ug0s = fast_sigmoid(au[0] + xu + b0u_c);
            Rbf0[swi] = cvt_bf16(rg * h0s);
        }
        if (l1) {
            float rg1 = fast_sigmoid(a1r[0] + br1c);
            ug1s = fast_sigmoid(a1u[0] + bu1c);
            Rbf1[swi] = cvt_bf16(rg1 * h1s);
        }
        sync_lds();

        // ---- Phase B: both o gates + both h updates
        floatx4 ao = (floatx4)0.f;
        if (l0) {
#pragma unroll
            for (int kk = 0; kk < 4; ++kk)
                MFMA16(ao, ldsA_r4(Rbf0, l15, kk, quad), B0o[kk]);
        }
        if (l1) {
#pragma unroll
            for (int kk = 0; kk < 4; ++kk)
                MFMA16(axo, ldsA_r4(Rbf1, l15, kk, quad), B1o[kk]);
        }
        if (l0) {
            float og = fast_tanh(ao[0] + xo + b0o_c);
            h0s = h0s + ug0s * (og - h0s);
            Hbf0[swi] = cvt_bf16(h0s);
        }
        if (l1) {
            float og1 = fast_tanh(axo[0] + bo1c);
            h1s = h1s + ug1s * (og1 - h1s);
            Hbf1[swi] = cvt_bf16(h1s);
        }
        if (pf) { xr = nr; xu = nu; xo = no; }
        sync_lds();
    }

    H1fin[(size_t)(b0 + quad) * HID + c] = h1s;
}

// ---------------------------------------------------------------------------
// Classifier: out[b][c] = bfc[c] + sum_k H1[b][k] * Wfc[k][c]
// ---------------------------------------------------------------------------
__global__ __launch_bounds__(256) void cls_kernel(
    const float* __restrict__ H1, const float* __restrict__ Wfc,
    const float* __restrict__ bfc, float* __restrict__ out)
{
    const int b = blockIdx.x;
    const int tid = threadIdx.x;
    __shared__ float h[HID];
    if (tid < HID) h[tid] = H1[(size_t)b * HID + tid];
    __syncthreads();
    for (int c = tid; c < NCLS; c += 256) {
        float a = bfc[c];
#pragma unroll 8
        for (int k = 0; k < HID; ++k)
            a += h[k] * Wfc[(size_t)k * NCLS + c];
        out[(size_t)b * NCLS + c] = a;
    }
}

// ---------------------------------------------------------------------------
extern "C" void kernel_launch(void* const* d_in, const int* in_sizes, int n_in,
                              void* d_out, int out_size, void* d_ws, size_t ws_size,
                              hipStream_t stream)
{
    const float* X   = (const float*)d_in[0];
    const float* Wr0 = (const float*)d_in[1];
    const float* br0 = (const float*)d_in[2];
    const float* Wu0 = (const float*)d_in[3];
    const float* bu0 = (const float*)d_in[4];
    const float* Wo0 = (const float*)d_in[5];
    const float* bo0 = (const float*)d_in[6];
    const float* Wr1 = (const float*)d_in[7];
    const float* br1 = (const float*)d_in[8];
    const float* Wu1 = (const float*)d_in[9];
    const float* bu1 = (const float*)d_in[10];
    const float* Wo1 = (const float*)d_in[11];
    const float* bo1 = (const float*)d_in[12];
    const float* Wfc = (const float*)d_in[13];
    const float* bfc = (const float*)d_in[14];
    float* out = (float*)d_out;

    // workspace:
    //   XG  fp32 [64][281][4][384]  110,493,696 B  (gemm_bx output, gru input)
    //   H1fin fp32 [256][128]           131,072 B
    //   Wt0 bf16 [3*128*288]            221,184 B
    //   Wh0/Wx1/Wh1 bf16 [384*128]       98,304 B each
    char* ws = (char*)d_ws;
    float*          XG    = (float*)ws;
    float*          H1fin = (float*)(ws + (size_t)SEQ * 64 * 1536 * 4);
    unsigned short* Wt0   = (unsigned short*)(ws + (size_t)SEQ * 64 * 1536 * 4 + (size_t)BATCH * HID * 4);
    unsigned short* Wh0   = Wt0 + (size_t)3 * HID * KPAD0;
    unsigned short* Wx1   = Wh0 + (size_t)384 * HID;
    unsigned short* Wh1   = Wx1 + (size_t)384 * HID;

    wt_kernel<<<dim3(12, 32), 256, 0, stream>>>(Wr0, Wu0, Wo0, Wr1, Wu1, Wo1,
                                                Wt0, Wh0, Wx1, Wh1);
    gemm_bx  <<<dim3(BATCH, 5), 256, 0, stream>>>(X, Wt0, XG);
    gru_fused<<<dim3(64), 512, 0, stream>>>(Wh0, Wx1, Wh1, XG,
                                            br0, bu0, bo0, br1, bu1, bo1, H1fin);
    cls_kernel<<<dim3(BATCH), 256, 0, stream>>>(H1fin, Wfc, bfc, out);
}

// Round 8
// 507.180 us; speedup vs baseline: 3.1185x; 1.1295x over previous
//
#include <hip/hip_runtime.h>
#include <math.h>

#define HID    128
#define IN_CH  271
#define SEQ    281
#define NCLS   1854
#define BATCH  256
#define M_TOT  (SEQ * BATCH)          // 71936 = 562 * 128
#define KPAD0  288                    // 271 padded to 9*32

typedef __attribute__((ext_vector_type(8))) short short8;
typedef __attribute__((ext_vector_type(4))) float floatx4;

#define MFMA16(acc, a, b) acc = __builtin_amdgcn_mfma_f32_16x16x32_bf16((a), (b), (acc), 0, 0, 0)

__device__ __forceinline__ unsigned short f2bf(float f) {
    union { float f; unsigned u; } v; v.f = f;
    unsigned u = v.u;
    u += 0x7FFF + ((u >> 16) & 1);        // RNE
    return (unsigned short)(u >> 16);
}
// single-instruction bf16 convert (RNE, bit-identical to f2bf for finite vals)
__device__ __forceinline__ unsigned short cvt_bf16(float f) {
    unsigned r;
    asm("v_cvt_pk_bf16_f32 %0, %1, %1" : "=v"(r) : "v"(f));
    return (unsigned short)r;
}
__device__ __forceinline__ float fast_rcp(float x) {
    float r;
    asm("v_rcp_f32 %0, %1" : "=v"(r) : "v"(x));
    return r;
}
__device__ __forceinline__ float fast_sigmoid(float s) {
    return fast_rcp(1.f + __expf(-s));
}
// tanh(x) = 2/(1+e^{-2x}) - 1 ; exp limits give exactly -1/+1, branch-free
__device__ __forceinline__ float fast_tanh(float s) {
    float e = __expf(-2.f * s);
    return __builtin_fmaf(2.f, fast_rcp(1.f + e), -1.f);
}
// LDS-only barrier: waits ds-ops but does NOT drain vmcnt.
__device__ __forceinline__ void sync_lds() {
    asm volatile("s_waitcnt lgkmcnt(0)\n\ts_barrier" ::: "memory");
}

// ---------------------------------------------------------------------------
// 4-row swizzled LDS h-tile (R2-verified: SQ_LDS_BANK_CONFLICT = 0):
//   element (row, k) at  row*128 + (((k>>3) ^ (2*row)) << 3) + (k&7)
// ---------------------------------------------------------------------------
__device__ __forceinline__ short8 ldsA_r4(const unsigned short* base, int l15, int kk, int quad) {
    const int row4  = l15 >> 2;
    const int chunk = (4 * kk + quad) ^ (row4 << 1);
    return *(const short8*)(base + row4 * 128 + (chunk << 3));
}
__device__ __forceinline__ int sw_idx4(int row, int c) {
    return row * 128 + ((((c >> 3) ^ (row << 1)) << 3) | (c & 7));
}

// ---------------------------------------------------------------------------
// Transpose+convert X: X[b][k][t] fp32 -> Abf[(b*281+t)*288 + k] bf16.
// (R4-proven, ~10 us)
// ---------------------------------------------------------------------------
__global__ __launch_bounds__(256) void xt_kernel(
    const float* __restrict__ X, unsigned short* __restrict__ Abf)
{
    const int tb = blockIdx.x;            // 0..4, t-tile of 64
    const int b  = blockIdx.y;
    const int tid = threadIdx.x;
    const int t0 = tb * 64;
    const float* __restrict__ Xb = X + (size_t)b * (IN_CH * SEQ);

    __shared__ float Xl[32][65];

    for (int kc = 0; kc < KPAD0 / 32; ++kc) {
#pragma unroll
        for (int r = 0; r < 8; ++r) {
            int e = tid + 256 * r;
            int kk = e >> 6, tt = e & 63;
            int k = kc * 32 + kk, t = t0 + tt;
            Xl[kk][tt] = (k < IN_CH && t < SEQ) ? Xb[k * SEQ + t] : 0.f;
        }
        __syncthreads();
        {
            int tt = tid >> 2, part = tid & 3;
            int t = t0 + tt;
            if (t < SEQ) {
                union { unsigned short s[8]; uint4 v; } u;
#pragma unroll
                for (int i = 0; i < 8; ++i) u.s[i] = f2bf(Xl[part * 8 + i][tt]);
                *(uint4*)(Abf + ((size_t)b * SEQ + t) * KPAD0 + kc * 32 + part * 8) = u.v;
            }
        }
        __syncthreads();
    }
}

// ---------------------------------------------------------------------------
// Weight transpose+convert. grid (12, 32), blockIdx.y = n-slice of 4.
// blk 0..2 : Wt0 [n][288]        = W0g[k][n], k<271, zero-padded (gemm B)
// blk 3..5 : Wh0 [g*128+n][128]  = W0g[271+k][n]     (gru, layer0 h-part)
// blk 6..8 : Wx1 [g*128+n][128]  = W1g[k][n]         (gru, layer1 x-part)
// blk 9..11: Wh1 [g*128+n][128]  = W1g[128+k][n]     (gru, layer1 h-part)
// ---------------------------------------------------------------------------
__global__ __launch_bounds__(256) void wt_kernel(
    const float* __restrict__ Wr0, const float* __restrict__ Wu0, const float* __restrict__ Wo0,
    const float* __restrict__ Wr1, const float* __restrict__ Wu1, const float* __restrict__ Wo1,
    unsigned short* __restrict__ Wt0, unsigned short* __restrict__ Wh0,
    unsigned short* __restrict__ Wx1, unsigned short* __restrict__ Wh1)
{
    const int blk  = blockIdx.x;
    const int kind = blk / 3, g = blk % 3;
    const int tid  = threadIdx.x;
    const int n0   = blockIdx.y * 4;

    const float* __restrict__ W =
        (kind <= 1) ? ((g == 0) ? Wr0 : (g == 1) ? Wu0 : Wo0)
                    : ((g == 0) ? Wr1 : (g == 1) ? Wu1 : Wo1);

    if (kind == 0) {
        unsigned short* __restrict__ out = Wt0 + (size_t)g * HID * KPAD0;
        for (int n = n0; n < n0 + 4; ++n)
            for (int k = tid; k < KPAD0; k += 256) {
                float v = (k < IN_CH) ? W[(size_t)k * HID + n] : 0.f;
                out[(size_t)n * KPAD0 + k] = f2bf(v);
            }
    } else {
        const int rbase = (kind == 1) ? IN_CH : (kind == 2) ? 0 : HID;
        unsigned short* __restrict__ out =
            ((kind == 1) ? Wh0 : (kind == 2) ? Wx1 : Wh1) + (size_t)g * HID * HID;
        for (int n = n0; n < n0 + 4; ++n)
            for (int k = tid; k < HID; k += 256)
                out[(size_t)n * HID + k] = f2bf(W[(size_t)(rbase + k) * HID + n]);
    }
}

// ---------------------------------------------------------------------------
// bf16 MFMA GEMM (layer-0 x-contributions only) — R4-proven structure.
// Logical row m' = t*256 + b; tile m0 = blk*128 -> tt = m0>>8, b0m = m0&255.
// R8 changes vs R4: (a) bias dropped (gru folds it); (b) epilogue stores to
// the R7 XG layout [b>>2][t][b&3][chan]: acc float4 = 4 consecutive b ->
// 4 scalar stores at stride 384 floats; per store inst lanes l15 span 16
// consecutive chans = 64B segments (same pattern as R7's gemm — fine).
// ---------------------------------------------------------------------------
__global__ __launch_bounds__(256) void gemm_xg(
    const unsigned short* __restrict__ A,
    const unsigned short* __restrict__ Wt,
    float* __restrict__ XG)
{
    const int g = blockIdx.y;
    const unsigned short* __restrict__ B = Wt + (size_t)g * HID * KPAD0;

    __shared__ unsigned short As[128 * 40];
    __shared__ unsigned short Bs[128 * 40];

    const int tid   = threadIdx.x;
    const int lane  = tid & 63;
    const int wave  = tid >> 6;
    const int l15   = lane & 15;
    const int quad  = lane >> 4;
    const int mhalf = wave >> 1;
    const int nhalf = wave & 1;
    const int m0    = blockIdx.x * 128;
    const int tt    = m0 >> 8;
    const int b0m   = m0 & 255;

    floatx4 acc[4][4];
#pragma unroll
    for (int im = 0; im < 4; ++im)
#pragma unroll
        for (int in = 0; in < 4; ++in) acc[im][in] = (floatx4)0.f;

    const int r0 = tid >> 2, p0 = tid & 3;
    const int r1 = (tid + 256) >> 2, p1 = tid & 3;

    for (int kt = 0; kt < KPAD0 / 32; ++kt) {
        if (kt) __syncthreads();
        const int kb = kt * 32;
        uint4 va0 = *(const uint4*)(A + ((size_t)(b0m + r0) * SEQ + tt) * KPAD0 + kb + p0 * 8);
        uint4 va1 = *(const uint4*)(A + ((size_t)(b0m + r1) * SEQ + tt) * KPAD0 + kb + p1 * 8);
        uint4 vb0 = *(const uint4*)(B + (size_t)r0 * KPAD0 + kb + p0 * 8);
        uint4 vb1 = *(const uint4*)(B + (size_t)r1 * KPAD0 + kb + p1 * 8);
        *(uint4*)(As + r0 * 40 + p0 * 8) = va0;
        *(uint4*)(As + r1 * 40 + p1 * 8) = va1;
        *(uint4*)(Bs + r0 * 40 + p0 * 8) = vb0;
        *(uint4*)(Bs + r1 * 40 + p1 * 8) = vb1;
        __syncthreads();

        short8 af[4], bf[4];
#pragma unroll
        for (int im = 0; im < 4; ++im)
            af[im] = *(const short8*)(As + (mhalf * 64 + im * 16 + l15) * 40 + quad * 8);
#pragma unroll
        for (int in = 0; in < 4; ++in)
            bf[in] = *(const short8*)(Bs + (nhalf * 64 + in * 16 + l15) * 40 + quad * 8);
#pragma unroll
        for (int im = 0; im < 4; ++im)
#pragma unroll
            for (int in = 0; in < 4; ++in)
                MFMA16(acc[im][in], af[im], bf[in]);
    }

    // epilogue: XG[(bb>>2)][tt][j][g*128+n] = acc[im][in][j]  (raw, no bias)
#pragma unroll
    for (int im = 0; im < 4; ++im) {
        const int bb = b0m + mhalf * 64 + im * 16 + quad * 4;   // 4-aligned
        const size_t rbase = ((size_t)(bb >> 2) * SEQ + tt) * 1536;
#pragma unroll
        for (int in = 0; in < 4; ++in) {
            const int chan = g * HID + nhalf * 64 + in * 16 + l15;
            float* dst = XG + rbase + chan;
#pragma unroll
            for (int j = 0; j < 4; ++j)
                dst[j * 384] = acc[im][in][j];
        }
    }
}

// ---------------------------------------------------------------------------
// FUSED 2-layer GRU — 64 blocks x 4 batch rows, skewed 2-phase pipeline.
// R7-measured: 252 us, VGPR 116, conflicts 0 — best gru; UNCHANGED here.
// At structural floor for bf16 16x16x32: per-CU 288 MFMA/iter (invariant in
// rows/block since rows*blocks = BATCH) = 72/SIMD ~ 1400cy issue (164 us)
// + ~90 us 2-barrier round-trip latency.  Layer-0 bias folded here.
// ---------------------------------------------------------------------------
__global__ __launch_bounds__(512, 1) void gru_fused(
    const unsigned short* __restrict__ Wh0,
    const unsigned short* __restrict__ Wx1,
    const unsigned short* __restrict__ Wh1,
    const float* __restrict__ XG,
    const float* __restrict__ br0, const float* __restrict__ bu0, const float* __restrict__ bo0,
    const float* __restrict__ br1, const float* __restrict__ bu1, const float* __restrict__ bo1,
    float* __restrict__ H1fin)
{
    const int b0   = blockIdx.x * 4;
    const int tid  = threadIdx.x;
    const int w    = tid >> 6;        // 0..7
    const int lane = tid & 63;
    const int l15  = lane & 15;
    const int quad = lane >> 4;       // this lane's batch row 0..3
    const int c    = w * 16 + l15;    // this lane's column 0..127

    __shared__ __attribute__((aligned(16))) unsigned short Hbf0[4 * 128];
    __shared__ __attribute__((aligned(16))) unsigned short Rbf0[4 * 128];
    __shared__ __attribute__((aligned(16))) unsigned short Hbf1[4 * 128];
    __shared__ __attribute__((aligned(16))) unsigned short Rbf1[4 * 128];

    // hoisted weight B-fragments: 9 (layer,gate) tiles x 4 k-steps
    short8 B0r[4], B0u[4], B0o[4], Bxr[4], Bxu[4], Bxo[4], B1r[4], B1u[4], B1o[4];
#pragma unroll
    for (int kk = 0; kk < 4; ++kk) {
        const size_t off = (size_t)c * HID + kk * 32 + quad * 8;
        B0r[kk] = *(const short8*)(Wh0 + off);
        B0u[kk] = *(const short8*)(Wh0 + (size_t)128 * HID + off);
        B0o[kk] = *(const short8*)(Wh0 + (size_t)256 * HID + off);
        Bxr[kk] = *(const short8*)(Wx1 + off);
        Bxu[kk] = *(const short8*)(Wx1 + (size_t)128 * HID + off);
        Bxo[kk] = *(const short8*)(Wx1 + (size_t)256 * HID + off);
        B1r[kk] = *(const short8*)(Wh1 + off);
        B1u[kk] = *(const short8*)(Wh1 + (size_t)128 * HID + off);
        B1o[kk] = *(const short8*)(Wh1 + (size_t)256 * HID + off);
    }

    for (int idx = tid; idx < 4 * 128; idx += 512) {
        Hbf0[idx] = 0; Rbf0[idx] = 0; Hbf1[idx] = 0; Rbf1[idx] = 0;
    }

    float h0s = 0.f, h1s = 0.f, ug0s = 0.f, ug1s = 0.f;

    const float b0r_c = br0[c], b0u_c = bu0[c], b0o_c = bo0[c];
    const float br1c = br1[c], bu1c = bu1[c], bo1c = bo1[c];

    // swizzled write index for this lane's single cell (row=quad, col=c)
    const int swi = sw_idx4(quad, c);

    // XG [gb][t][r=quad][chan]: lane reads chan=c (+128,+256)
    const float* xgp = XG + (size_t)blockIdx.x * SEQ * 1536 + quad * 384 + c;
    float xr = xgp[0];
    float xu = xgp[128];
    float xo = xgp[256];
    xgp += 1536;
    __syncthreads();

    for (int i = 0; i <= SEQ; ++i) {
        const bool l0 = (i < SEQ);     // layer 0 computes step i
        const bool l1 = (i > 0);       // layer 1 computes step i-1

        // prefetch xg(i+1) — lands during this step's compute
        float nr, nu, no;
        const bool pf = (i + 1 < SEQ);
        if (pf) {
            nr = xgp[0];
            nu = xgp[128];
            no = xgp[256];
            xgp += 1536;
        }

        // ---- Phase A: single read of h0(i-1)/h1(i-2); all r,u gates + L1 o-x part
        short8 a0[4], a1[4];
#pragma unroll
        for (int kk = 0; kk < 4; ++kk) {
            a0[kk] = ldsA_r4(Hbf0, l15, kk, quad);
            a1[kk] = ldsA_r4(Hbf1, l15, kk, quad);
        }
        floatx4 ar = (floatx4)0.f, au = (floatx4)0.f;
        floatx4 a1r = (floatx4)0.f, a1u = (floatx4)0.f, axo = (floatx4)0.f;
        if (l0) {
#pragma unroll
            for (int kk = 0; kk < 4; ++kk) {
                MFMA16(ar, a0[kk], B0r[kk]);
                MFMA16(au, a0[kk], B0u[kk]);
            }
        }
        if (l1) {
#pragma unroll
            for (int kk = 0; kk < 4; ++kk) {
                MFMA16(a1r, a0[kk], Bxr[kk]);
                MFMA16(a1u, a0[kk], Bxu[kk]);
                MFMA16(axo, a0[kk], Bxo[kk]);
                MFMA16(a1r, a1[kk], B1r[kk]);
                MFMA16(a1u, a1[kk], B1u[kk]);
            }
        }
        if (l0) {
            float rg = fast_sigmoid(ar[0] + xr + b0r_c);
            ug0s = fast_sigmoid(au[0] + xu + b0u_c);
            Rbf0[swi] = cvt_bf16(rg * h0s);
        }
        if (l1) {
            float rg1 = fast_sigmoid(a1r[0] + br1c);
            ug1s = fast_sigmoid(a1u[0] + bu1c);
            Rbf1[swi] = cvt_bf16(rg1 * h1s);
        }
        sync_lds();

        // ---- Phase B: both o gates + both h updates
        floatx4 ao = (floatx4)0.f;
        if (l0) {
#pragma unroll
            for (int kk = 0; kk < 4; ++kk)
                MFMA16(ao, ldsA_r4(Rbf0, l15, kk, quad), B0o[kk]);
        }
        if (l1) {
#pragma unroll
            for (int kk = 0; kk < 4; ++kk)
                MFMA16(axo, ldsA_r4(Rbf1, l15, kk, quad), B1o[kk]);
        }
        if (l0) {
            float og = fast_tanh(ao[0] + xo + b0o_c);
            h0s = h0s + ug0s * (og - h0s);
            Hbf0[swi] = cvt_bf16(h0s);
        }
        if (l1) {
            float og1 = fast_tanh(axo[0] + bo1c);
            h1s = h1s + ug1s * (og1 - h1s);
            Hbf1[swi] = cvt_bf16(h1s);
        }
        if (pf) { xr = nr; xu = nu; xo = no; }
        sync_lds();
    }

    H1fin[(size_t)(b0 + quad) * HID + c] = h1s;
}

// ---------------------------------------------------------------------------
// Classifier: out[b][c] = bfc[c] + sum_k H1[b][k] * Wfc[k][c]
// ---------------------------------------------------------------------------
__global__ __launch_bounds__(256) void cls_kernel(
    const float* __restrict__ H1, const float* __restrict__ Wfc,
    const float* __restrict__ bfc, float* __restrict__ out)
{
    const int b = blockIdx.x;
    const int tid = threadIdx.x;
    __shared__ float h[HID];
    if (tid < HID) h[tid] = H1[(size_t)b * HID + tid];
    __syncthreads();
    for (int c = tid; c < NCLS; c += 256) {
        float a = bfc[c];
#pragma unroll 8
        for (int k = 0; k < HID; ++k)
            a += h[k] * Wfc[(size_t)k * NCLS + c];
        out[(size_t)b * NCLS + c] = a;
    }
}

// ---------------------------------------------------------------------------
extern "C" void kernel_launch(void* const* d_in, const int* in_sizes, int n_in,
                              void* d_out, int out_size, void* d_ws, size_t ws_size,
                              hipStream_t stream)
{
    const float* X   = (const float*)d_in[0];
    const float* Wr0 = (const float*)d_in[1];
    const float* br0 = (const float*)d_in[2];
    const float* Wu0 = (const float*)d_in[3];
    const float* bu0 = (const float*)d_in[4];
    const float* Wo0 = (const float*)d_in[5];
    const float* bo0 = (const float*)d_in[6];
    const float* Wr1 = (const float*)d_in[7];
    const float* br1 = (const float*)d_in[8];
    const float* Wu1 = (const float*)d_in[9];
    const float* bu1 = (const float*)d_in[10];
    const float* Wo1 = (const float*)d_in[11];
    const float* bo1 = (const float*)d_in[12];
    const float* Wfc = (const float*)d_in[13];
    const float* bfc = (const float*)d_in[14];
    float* out = (float*)d_out;

    // workspace:
    //   XG  fp32 [64][281][4][384]  110,493,696 B  ([b>>2][t][b&3][chan])
    //   Abf bf16 [M_TOT*288]         41,435,136 B  (H1fin aliases: dead after gemm)
    //   Wt0 bf16 [3*128*288]            221,184 B
    //   Wh0/Wx1/Wh1 bf16 [384*128]       98,304 B each
    char* ws = (char*)d_ws;
    float*          XG    = (float*)ws;
    unsigned short* Abf   = (unsigned short*)(ws + (size_t)M_TOT * 384 * 4);
    float*          H1fin = (float*)Abf;        // alias: Abf dead after gemm_xg
    unsigned short* Wt0   = (unsigned short*)(ws + (size_t)M_TOT * 384 * 4 + (size_t)M_TOT * KPAD0 * 2);
    unsigned short* Wh0   = Wt0 + (size_t)3 * HID * KPAD0;
    unsigned short* Wx1   = Wh0 + (size_t)384 * HID;
    unsigned short* Wh1   = Wx1 + (size_t)384 * HID;

    wt_kernel<<<dim3(12, 32), 256, 0, stream>>>(Wr0, Wu0, Wo0, Wr1, Wu1, Wo1,
                                                Wt0, Wh0, Wx1, Wh1);
    xt_kernel<<<dim3(5, BATCH), 256, 0, stream>>>(X, Abf);
    gemm_xg  <<<dim3(M_TOT / 128, 3), 256, 0, stream>>>(Abf, Wt0, XG);
    gru_fused<<<dim3(64), 512, 0, stream>>>(Wh0, Wx1, Wh1, XG,
                                            br0, bu0, bo0, br1, bu1, bo1, H1fin);
    cls_kernel<<<dim3(BATCH), 256, 0, stream>>>(H1fin, Wfc, bfc, out);
}